// Round 1
// baseline (287.411 us; speedup 1.0000x reference)
//
#include <hip/hip_runtime.h>
#include <stdint.h>

// ---------------- problem constants ----------------
#define BATCH  8
#define SEQ    1025
#define DMODEL 768
#define NHEAD  12
#define HDIM   64
#define MTOT   (BATCH * SEQ)   // 8200 tokens
#define MPAD   8320            // 65 * 128
#define SPAD   1056            // 33 * 32 (padded key length)
#define BHTOT  (BATCH * NHEAD) // 96
#define QTILES 65              // ceil(1025/16)

typedef __bf16 bf16x8 __attribute__((ext_vector_type(8)));
typedef __bf16 bf16x4 __attribute__((ext_vector_type(4)));
typedef float  f32x4  __attribute__((ext_vector_type(4)));

// ---------------- workspace layout (bytes) ----------------
// xb region is reused for the attention output (xb consumed before attn writes).
constexpr size_t XB_OFF  = 0;
constexpr size_t XB_SZ   = (size_t)MPAD * DMODEL * 2;      // 12,779,520
constexpr size_t W_SZ    = (size_t)DMODEL * DMODEL * 2;    //  1,179,648
constexpr size_t WQB_OFF = XB_OFF + XB_SZ;
constexpr size_t WKB_OFF = WQB_OFF + W_SZ;
constexpr size_t WVB_OFF = WKB_OFF + W_SZ;
constexpr size_t WPB_OFF = WVB_OFF + W_SZ;
constexpr size_t QB_OFF  = WPB_OFF + W_SZ;
constexpr size_t QB_SZ   = (size_t)BHTOT * SEQ * HDIM * 2; // 12,595,200
constexpr size_t KB_OFF  = QB_OFF + QB_SZ;
constexpr size_t VT_OFF  = KB_OFF + QB_SZ;
constexpr size_t VT_SZ   = (size_t)BHTOT * HDIM * SPAD * 2;
constexpr size_t AO_OFF  = XB_OFF;                          // alias
constexpr size_t WS_NEEDED = VT_OFF + VT_SZ;                // ~55.7 MB

// ---------------- helpers ----------------
__device__ __forceinline__ void async16(const void* g, void* l) {
  __builtin_amdgcn_global_load_lds((__attribute__((address_space(1))) void*)g,
                                   (__attribute__((address_space(3))) void*)l,
                                   16, 0, 0);
}

// ---------------- fp32 -> bf16 conversion (zero-fills dst beyond n_src) ----------------
__global__ void __launch_bounds__(256)
convert_f32_bf16(const float* __restrict__ src, __bf16* __restrict__ dst,
                 int n_src, int n_dst) {
  int idx = (blockIdx.x * 256 + threadIdx.x) * 4;
  if (idx >= n_dst) return;
  bf16x4 o;
  if (idx + 3 < n_src) {
    float4 v = *(const float4*)&src[idx];
    o[0] = (__bf16)v.x; o[1] = (__bf16)v.y; o[2] = (__bf16)v.z; o[3] = (__bf16)v.w;
  } else {
    #pragma unroll
    for (int t = 0; t < 4; ++t) {
      int k = idx + t;
      o[t] = (k < n_src) ? (__bf16)src[k] : (__bf16)0.f;
    }
  }
  *(bf16x4*)&dst[idx] = o;
}

// ---------------- shared 128x128 GEMM core: C = A @ W^T (both K-contiguous) ----------------
// A: [>=m0+128][DMODEL] bf16, W: [768][DMODEL] bf16. 4 waves, each 64x64 (4x4 MFMA frags).
__device__ __forceinline__ void gemm_core(const __bf16* __restrict__ A,
                                          const __bf16* __restrict__ W,
                                          __bf16* As, __bf16* Bs,
                                          int m0, int n0, f32x4 acc[4][4]) {
  const int tid  = threadIdx.x;
  const int lane = tid & 63;
  const int wave = tid >> 6;
  const int wm = wave >> 1, wn = wave & 1;
  const int l15 = lane & 15, lg = lane >> 4;

  for (int kt = 0; kt < DMODEL; kt += 64) {
    __syncthreads();   // protect LDS from previous iteration's readers
    #pragma unroll
    for (int i = 0; i < 4; ++i) {
      int e = (i * 256 + tid) * 8;       // element index in 128x64 tile
      int r = e >> 6, c = e & 63;
      async16(A + (size_t)(m0 + r) * DMODEL + kt + c, As + e);
      async16(W + (size_t)(n0 + r) * DMODEL + kt + c, Bs + e);
    }
    __syncthreads();   // compiler drains vmcnt(0) before s_barrier
    #pragma unroll
    for (int kk = 0; kk < 2; ++kk) {
      bf16x8 af[4], bfr[4];
      #pragma unroll
      for (int i = 0; i < 4; ++i)
        af[i] = *(const bf16x8*)&As[(wm * 64 + i * 16 + l15) * 64 + kk * 32 + lg * 8];
      #pragma unroll
      for (int j = 0; j < 4; ++j)
        bfr[j] = *(const bf16x8*)&Bs[(wn * 64 + j * 16 + l15) * 64 + kk * 32 + lg * 8];
      #pragma unroll
      for (int i = 0; i < 4; ++i)
        #pragma unroll
        for (int j = 0; j < 4; ++j)
          acc[i][j] = __builtin_amdgcn_mfma_f32_16x16x32_bf16(af[i], bfr[j], acc[i][j], 0, 0, 0);
    }
  }
}

// ---------------- QKV projection: z = {Q, K, V} ----------------
__global__ void __launch_bounds__(256)
gemm_qkv_kernel(const __bf16* __restrict__ xb,
                const __bf16* __restrict__ wqb, const __bf16* __restrict__ wkb,
                const __bf16* __restrict__ wvb,
                const float* __restrict__ bq, const float* __restrict__ bk,
                const float* __restrict__ bv,
                __bf16* __restrict__ qb, __bf16* __restrict__ kb,
                __bf16* __restrict__ vtb) {
  __shared__ __bf16 As[128 * 64];
  __shared__ __bf16 Bs[128 * 64];
  const int mode = blockIdx.z;
  const __bf16* W  = (mode == 0) ? wqb : (mode == 1) ? wkb : wvb;
  const float* bias = (mode == 0) ? bq : (mode == 1) ? bk : bv;
  const int m0 = blockIdx.x * 128, n0 = blockIdx.y * 128;

  f32x4 acc[4][4];
  #pragma unroll
  for (int i = 0; i < 4; ++i)
    #pragma unroll
    for (int j = 0; j < 4; ++j) acc[i][j] = (f32x4){0.f, 0.f, 0.f, 0.f};

  gemm_core(xb, W, As, Bs, m0, n0, acc);

  const int lane = threadIdx.x & 63;
  const int wave = threadIdx.x >> 6;
  const int wm = wave >> 1, wn = wave & 1;
  const int l15 = lane & 15, lg = lane >> 4;
  #pragma unroll
  for (int i = 0; i < 4; ++i) {
    #pragma unroll
    for (int j = 0; j < 4; ++j) {
      const int ncol = n0 + wn * 64 + j * 16 + l15;
      const float bb = bias[ncol];
      const int h = ncol >> 6, hd = ncol & 63;
      #pragma unroll
      for (int r = 0; r < 4; ++r) {
        const int mrow = m0 + wm * 64 + i * 16 + lg * 4 + r;
        if (mrow < MTOT) {
          const float val = acc[i][j][r] + bb;
          const int b = mrow / SEQ;
          const int s = mrow - b * SEQ;
          const int bh = b * NHEAD + h;
          if (mode == 2)
            vtb[((size_t)bh * HDIM + hd) * SPAD + s] = (__bf16)val;
          else if (mode == 0)
            qb[((size_t)bh * SEQ + s) * HDIM + hd] = (__bf16)val;
          else
            kb[((size_t)bh * SEQ + s) * HDIM + hd] = (__bf16)val;
        }
      }
    }
  }
}

// ---------------- output projection ----------------
__global__ void __launch_bounds__(256)
gemm_proj_kernel(const __bf16* __restrict__ ab, const __bf16* __restrict__ wpb,
                 const float* __restrict__ bp, float* __restrict__ out) {
  __shared__ __bf16 As[128 * 64];
  __shared__ __bf16 Bs[128 * 64];
  const int m0 = blockIdx.x * 128, n0 = blockIdx.y * 128;

  f32x4 acc[4][4];
  #pragma unroll
  for (int i = 0; i < 4; ++i)
    #pragma unroll
    for (int j = 0; j < 4; ++j) acc[i][j] = (f32x4){0.f, 0.f, 0.f, 0.f};

  gemm_core(ab, wpb, As, Bs, m0, n0, acc);

  const int lane = threadIdx.x & 63;
  const int wave = threadIdx.x >> 6;
  const int wm = wave >> 1, wn = wave & 1;
  const int l15 = lane & 15, lg = lane >> 4;
  #pragma unroll
  for (int i = 0; i < 4; ++i) {
    #pragma unroll
    for (int j = 0; j < 4; ++j) {
      const int ncol = n0 + wn * 64 + j * 16 + l15;
      const float bb = bp[ncol];
      #pragma unroll
      for (int r = 0; r < 4; ++r) {
        const int mrow = m0 + wm * 64 + i * 16 + lg * 4 + r;
        if (mrow < MTOT) out[(size_t)mrow * DMODEL + ncol] = acc[i][j][r] + bb;
      }
    }
  }
}

// ---------------- flash attention: 1 wave per (bh, 16-row q-tile) ----------------
__global__ void __launch_bounds__(64)
attn_kernel(const __bf16* __restrict__ qb, const __bf16* __restrict__ kb,
            const __bf16* __restrict__ vtb, __bf16* __restrict__ ao) {
  __shared__ __bf16 p_lds[16 * 32];
  const int lane = threadIdx.x;
  const int l15 = lane & 15, lg = lane >> 4;
  const int qt = blockIdx.x % QTILES;
  const int bh = blockIdx.x / QTILES;
  const __bf16* Qp = qb + (size_t)bh * SEQ * HDIM;
  const __bf16* Kp = kb + (size_t)bh * SEQ * HDIM;
  const __bf16* Vp = vtb + (size_t)bh * HDIM * SPAD;

  int qs = qt * 16 + l15;
  if (qs >= SEQ) qs = SEQ - 1;               // clamped garbage rows, masked at store
  bf16x8 qf[2];
  qf[0] = *(const bf16x8*)&Qp[(size_t)qs * HDIM + lg * 8];
  qf[1] = *(const bf16x8*)&Qp[(size_t)qs * HDIM + 32 + lg * 8];

  f32x4 accO[4];
  #pragma unroll
  for (int d = 0; d < 4; ++d) accO[d] = (f32x4){0.f, 0.f, 0.f, 0.f};
  float mrun[4], lrun[4];
  #pragma unroll
  for (int r = 0; r < 4; ++r) { mrun[r] = -1e30f; lrun[r] = 0.f; }

  const float scale = 0.125f;  // 1/sqrt(64)

  for (int kt = 0; kt < 33; ++kt) {
    const int k0 = kt * 32;
    // ---- scores: two 16-key halves ----
    f32x4 sc[2];
    #pragma unroll
    for (int half = 0; half < 2; ++half) {
      int ks = k0 + half * 16 + l15;
      int ksc = ks < SEQ ? ks : SEQ - 1;
      bf16x8 kf0 = *(const bf16x8*)&Kp[(size_t)ksc * HDIM + lg * 8];
      bf16x8 kf1 = *(const bf16x8*)&Kp[(size_t)ksc * HDIM + 32 + lg * 8];
      f32x4 a = (f32x4){0.f, 0.f, 0.f, 0.f};
      a = __builtin_amdgcn_mfma_f32_16x16x32_bf16(qf[0], kf0, a, 0, 0, 0);
      a = __builtin_amdgcn_mfma_f32_16x16x32_bf16(qf[1], kf1, a, 0, 0, 0);
      sc[half] = a;
    }
    const bool v0 = (k0 + l15) < SEQ;
    const bool v1 = (k0 + 16 + l15) < SEQ;

    float p0[4], p1[4];
    #pragma unroll
    for (int r = 0; r < 4; ++r) {
      float s0 = v0 ? sc[0][r] * scale : -1e30f;
      float s1 = v1 ? sc[1][r] * scale : -1e30f;
      float mx = fmaxf(s0, s1);
      #pragma unroll
      for (int off = 1; off < 16; off <<= 1)
        mx = fmaxf(mx, __shfl_xor(mx, off, 64));
      const float mnew = fmaxf(mrun[r], mx);
      const float p0v = __expf(s0 - mnew);
      const float p1v = __expf(s1 - mnew);
      float rsum = p0v + p1v;
      #pragma unroll
      for (int off = 1; off < 16; off <<= 1)
        rsum += __shfl_xor(rsum, off, 64);
      const float corr = __expf(mrun[r] - mnew);
      lrun[r] = lrun[r] * corr + rsum;
      mrun[r] = mnew;
      #pragma unroll
      for (int d = 0; d < 4; ++d) accO[d][r] *= corr;
      p0[r] = p0v; p1[r] = p1v;
    }

    // ---- transpose P (C/D layout -> A-frag layout) through LDS ----
    __syncthreads();  // WAR: prior iteration's pf reads done
    #pragma unroll
    for (int r = 0; r < 4; ++r) {
      p_lds[(lg * 4 + r) * 32 + l15]      = (__bf16)p0[r];
      p_lds[(lg * 4 + r) * 32 + 16 + l15] = (__bf16)p1[r];
    }
    __syncthreads();
    bf16x8 pf = *(const bf16x8*)&p_lds[l15 * 32 + lg * 8];

    // ---- PV: out(16x64) += P(16x32) @ V(32x64), V read transposed ----
    #pragma unroll
    for (int d = 0; d < 4; ++d) {
      bf16x8 vf = *(const bf16x8*)&Vp[(size_t)(d * 16 + l15) * SPAD + k0 + lg * 8];
      accO[d] = __builtin_amdgcn_mfma_f32_16x16x32_bf16(pf, vf, accO[d], 0, 0, 0);
    }
  }

  // ---- epilogue: normalize and store (b, s, h*64+d) bf16 ----
  const int h = bh % NHEAD;
  const int b = bh / NHEAD;
  #pragma unroll
  for (int r = 0; r < 4; ++r) {
    const float inv = 1.0f / lrun[r];
    const int srow = qt * 16 + lg * 4 + r;
    if (srow < SEQ) {
      #pragma unroll
      for (int d = 0; d < 4; ++d)
        ao[((size_t)b * SEQ + srow) * DMODEL + h * HDIM + d * 16 + l15] =
            (__bf16)(accO[d][r] * inv);
    }
  }
}

// ---------------- launcher ----------------
extern "C" void kernel_launch(void* const* d_in, const int* in_sizes, int n_in,
                              void* d_out, int out_size, void* d_ws, size_t ws_size,
                              hipStream_t stream) {
  const float* x  = (const float*)d_in[0];
  const float* Wk = (const float*)d_in[1];
  const float* bk = (const float*)d_in[2];
  const float* Wq = (const float*)d_in[3];
  const float* bq = (const float*)d_in[4];
  const float* Wv = (const float*)d_in[5];
  const float* bv = (const float*)d_in[6];
  const float* Wp = (const float*)d_in[7];
  const float* bp = (const float*)d_in[8];
  float* out = (float*)d_out;

  if (ws_size < WS_NEEDED) return;  // fail loudly via validation

  char* ws = (char*)d_ws;
  __bf16* xb  = (__bf16*)(ws + XB_OFF);
  __bf16* wqb = (__bf16*)(ws + WQB_OFF);
  __bf16* wkb = (__bf16*)(ws + WKB_OFF);
  __bf16* wvb = (__bf16*)(ws + WVB_OFF);
  __bf16* wpb = (__bf16*)(ws + WPB_OFF);
  __bf16* qb  = (__bf16*)(ws + QB_OFF);
  __bf16* kb  = (__bf16*)(ws + KB_OFF);
  __bf16* vtb = (__bf16*)(ws + VT_OFF);
  __bf16* ab  = (__bf16*)(ws + AO_OFF);  // aliases xb (xb fully consumed first)

  // bf16 conversions
  {
    const int n_src = MTOT * DMODEL, n_dst = MPAD * DMODEL;
    convert_f32_bf16<<<dim3((n_dst / 4 + 255) / 256), dim3(256), 0, stream>>>(x, xb, n_src, n_dst);
    const int nw = DMODEL * DMODEL;
    const dim3 wg((nw / 4 + 255) / 256);
    convert_f32_bf16<<<wg, dim3(256), 0, stream>>>(Wq, wqb, nw, nw);
    convert_f32_bf16<<<wg, dim3(256), 0, stream>>>(Wk, wkb, nw, nw);
    convert_f32_bf16<<<wg, dim3(256), 0, stream>>>(Wv, wvb, nw, nw);
    convert_f32_bf16<<<wg, dim3(256), 0, stream>>>(Wp, wpb, nw, nw);
  }

  gemm_qkv_kernel<<<dim3(MPAD / 128, DMODEL / 128, 3), dim3(256), 0, stream>>>(
      xb, wqb, wkb, wvb, bq, bk, bv, qb, kb, vtb);

  attn_kernel<<<dim3(BHTOT * QTILES), dim3(64), 0, stream>>>(qb, kb, vtb, ab);

  gemm_proj_kernel<<<dim3(MPAD / 128, DMODEL / 128), dim3(256), 0, stream>>>(
      ab, wpb, bp, out);
}

// Round 3
// 246.057 us; speedup vs baseline: 1.1681x; 1.1681x over previous
//
#include <hip/hip_runtime.h>
#include <stdint.h>

// ---------------- problem constants ----------------
#define BATCH  8
#define SEQ    1025
#define DMODEL 768
#define NHEAD  12
#define HDIM   64
#define MTOT   (BATCH * SEQ)   // 8200 tokens
#define MPAD   8320            // 65 * 128
#define SPAD   1056            // 33 * 32 (padded key length)
#define BHTOT  (BATCH * NHEAD) // 96
#define QT32   33              // ceil(1025/32) q-tiles of 32
#define QKSCALE 0.18033688011112042f   // 0.125 * log2(e) -> exp2-domain softmax

typedef __bf16 bf16x8 __attribute__((ext_vector_type(8)));
typedef __bf16 bf16x4 __attribute__((ext_vector_type(4)));
typedef float  f32x4  __attribute__((ext_vector_type(4)));
typedef float  f32x16 __attribute__((ext_vector_type(16)));

// ---------------- workspace layout (bytes) ----------------
constexpr size_t XB_OFF  = 0;
constexpr size_t XB_SZ   = (size_t)MPAD * DMODEL * 2;
constexpr size_t W_SZ    = (size_t)DMODEL * DMODEL * 2;
constexpr size_t WQB_OFF = XB_OFF + XB_SZ;
constexpr size_t WKB_OFF = WQB_OFF + W_SZ;
constexpr size_t WVB_OFF = WKB_OFF + W_SZ;
constexpr size_t WPB_OFF = WVB_OFF + W_SZ;
constexpr size_t QB_OFF  = WPB_OFF + W_SZ;
constexpr size_t QB_SZ   = (size_t)BHTOT * SEQ * HDIM * 2;
constexpr size_t KB_OFF  = QB_OFF + QB_SZ;
constexpr size_t VT_OFF  = KB_OFF + QB_SZ;
constexpr size_t VT_SZ   = (size_t)BHTOT * HDIM * SPAD * 2;
constexpr size_t AO_OFF  = XB_OFF;                          // alias: xb consumed before attn writes
constexpr size_t WS_NEEDED = VT_OFF + VT_SZ;

// ---------------- helpers ----------------
__device__ __forceinline__ void async16(const void* g, void* l) {
  __builtin_amdgcn_global_load_lds((__attribute__((address_space(1))) void*)g,
                                   (__attribute__((address_space(3))) void*)l,
                                   16, 0, 0);
}

// pack two f32 -> bf16x2 dword (lo = first arg). Scalar casts: compiler emits
// cvt_pk (m240: hand-asm cvt_pk was slower; casts are unambiguous).
__device__ __forceinline__ unsigned pkbf(float lo, float hi) {
  __bf16 l = (__bf16)lo, h = (__bf16)hi;
  unsigned short lb = __builtin_bit_cast(unsigned short, l);
  unsigned short hb = __builtin_bit_cast(unsigned short, h);
  return ((unsigned)hb << 16) | (unsigned)lb;
}
__device__ __forceinline__ unsigned shfl32u(unsigned x) {   // partner half's value
  return (unsigned)__shfl_xor((int)x, 32, 64);
}
__device__ __forceinline__ float pairmax(float x) {  // max(own, lane^32)
  return fmaxf(x, __shfl_xor(x, 32, 64));
}
__device__ __forceinline__ float pairsum(float x) {  // own + lane^32
  return x + __shfl_xor(x, 32, 64);
}

// ---------------- fp32 -> bf16 conversion (zero-fills dst beyond n_src) ----------------
__global__ void __launch_bounds__(256)
convert_f32_bf16(const float* __restrict__ src, __bf16* __restrict__ dst,
                 int n_src, int n_dst) {
  int idx = (blockIdx.x * 256 + threadIdx.x) * 4;
  if (idx >= n_dst) return;
  bf16x4 o;
  if (idx + 3 < n_src) {
    float4 v = *(const float4*)&src[idx];
    o[0] = (__bf16)v.x; o[1] = (__bf16)v.y; o[2] = (__bf16)v.z; o[3] = (__bf16)v.w;
  } else {
    #pragma unroll
    for (int t = 0; t < 4; ++t) {
      int k = idx + t;
      o[t] = (k < n_src) ? (__bf16)src[k] : (__bf16)0.f;
    }
  }
  *(bf16x4*)&dst[idx] = o;
}

// 4 weight matrices in one launch; dst regions are contiguous (WQB..WPB).
__global__ void __launch_bounds__(256)
convert_w4(const float* __restrict__ w0, const float* __restrict__ w1,
           const float* __restrict__ w2, const float* __restrict__ w3,
           __bf16* __restrict__ dst) {
  const int which = blockIdx.y;
  const float* src = (which == 0) ? w0 : (which == 1) ? w1 : (which == 2) ? w2 : w3;
  __bf16* d = dst + (size_t)which * DMODEL * DMODEL;
  int idx = (blockIdx.x * 256 + threadIdx.x) * 4;
  if (idx >= DMODEL * DMODEL) return;
  float4 v = *(const float4*)&src[idx];
  bf16x4 o;
  o[0] = (__bf16)v.x; o[1] = (__bf16)v.y; o[2] = (__bf16)v.z; o[3] = (__bf16)v.w;
  *(bf16x4*)&d[idx] = o;
}

// ---------------- shared 128x128 GEMM core: C = A @ W^T ----------------
__device__ __forceinline__ void gemm_core(const __bf16* __restrict__ A,
                                          const __bf16* __restrict__ W,
                                          __bf16* As, __bf16* Bs,
                                          int m0, int n0, f32x4 acc[4][4]) {
  const int tid  = threadIdx.x;
  const int lane = tid & 63;
  const int wave = tid >> 6;
  const int wm = wave >> 1, wn = wave & 1;
  const int l15 = lane & 15, lg = lane >> 4;

  for (int kt = 0; kt < DMODEL; kt += 64) {
    __syncthreads();
    #pragma unroll
    for (int i = 0; i < 4; ++i) {
      int e = (i * 256 + tid) * 8;
      int r = e >> 6, c = e & 63;
      async16(A + (size_t)(m0 + r) * DMODEL + kt + c, As + e);
      async16(W + (size_t)(n0 + r) * DMODEL + kt + c, Bs + e);
    }
    __syncthreads();
    #pragma unroll
    for (int kk = 0; kk < 2; ++kk) {
      bf16x8 af[4], bfr[4];
      #pragma unroll
      for (int i = 0; i < 4; ++i)
        af[i] = *(const bf16x8*)&As[(wm * 64 + i * 16 + l15) * 64 + kk * 32 + lg * 8];
      #pragma unroll
      for (int j = 0; j < 4; ++j)
        bfr[j] = *(const bf16x8*)&Bs[(wn * 64 + j * 16 + l15) * 64 + kk * 32 + lg * 8];
      #pragma unroll
      for (int i = 0; i < 4; ++i)
        #pragma unroll
        for (int j = 0; j < 4; ++j)
          acc[i][j] = __builtin_amdgcn_mfma_f32_16x16x32_bf16(af[i], bfr[j], acc[i][j], 0, 0, 0);
    }
  }
}

// ---------------- QKV projection ----------------
__global__ void __launch_bounds__(256)
gemm_qkv_kernel(const __bf16* __restrict__ xb,
                const __bf16* __restrict__ wqb, const __bf16* __restrict__ wkb,
                const __bf16* __restrict__ wvb,
                const float* __restrict__ bq, const float* __restrict__ bk,
                const float* __restrict__ bv,
                __bf16* __restrict__ qb, __bf16* __restrict__ kb,
                __bf16* __restrict__ vtb) {
  __shared__ __bf16 As[128 * 64];
  __shared__ __bf16 Bs[128 * 64];
  const int mode = blockIdx.z;
  const __bf16* W  = (mode == 0) ? wqb : (mode == 1) ? wkb : wvb;
  const float* bias = (mode == 0) ? bq : (mode == 1) ? bk : bv;
  const int m0 = blockIdx.x * 128, n0 = blockIdx.y * 128;

  f32x4 acc[4][4];
  #pragma unroll
  for (int i = 0; i < 4; ++i)
    #pragma unroll
    for (int j = 0; j < 4; ++j) acc[i][j] = (f32x4){0.f, 0.f, 0.f, 0.f};

  gemm_core(xb, W, As, Bs, m0, n0, acc);

  const int lane = threadIdx.x & 63;
  const int wave = threadIdx.x >> 6;
  const int wm = wave >> 1, wn = wave & 1;
  const int l15 = lane & 15, lg = lane >> 4;
  #pragma unroll
  for (int i = 0; i < 4; ++i) {
    #pragma unroll
    for (int j = 0; j < 4; ++j) {
      const int ncol = n0 + wn * 64 + j * 16 + l15;
      const float bb = bias[ncol];
      const int h = ncol >> 6, hd = ncol & 63;
      #pragma unroll
      for (int r = 0; r < 4; ++r) {
        const int mrow = m0 + wm * 64 + i * 16 + lg * 4 + r;
        if (mrow < MTOT) {
          float val = acc[i][j][r] + bb;
          const int b = mrow / SEQ;
          const int s = mrow - b * SEQ;
          const int bh = b * NHEAD + h;
          if (mode == 2)
            vtb[((size_t)bh * HDIM + hd) * SPAD + s] = (__bf16)val;
          else if (mode == 0)
            qb[((size_t)bh * SEQ + s) * HDIM + hd] = (__bf16)(val * QKSCALE);
          else
            kb[((size_t)bh * SEQ + s) * HDIM + hd] = (__bf16)val;
        }
      }
    }
  }
}

// ---------------- output projection ----------------
__global__ void __launch_bounds__(256)
gemm_proj_kernel(const __bf16* __restrict__ ab, const __bf16* __restrict__ wpb,
                 const float* __restrict__ bp, float* __restrict__ out) {
  __shared__ __bf16 As[128 * 64];
  __shared__ __bf16 Bs[128 * 64];
  const int m0 = blockIdx.x * 128, n0 = blockIdx.y * 128;

  f32x4 acc[4][4];
  #pragma unroll
  for (int i = 0; i < 4; ++i)
    #pragma unroll
    for (int j = 0; j < 4; ++j) acc[i][j] = (f32x4){0.f, 0.f, 0.f, 0.f};

  gemm_core(ab, wpb, As, Bs, m0, n0, acc);

  const int lane = threadIdx.x & 63;
  const int wave = threadIdx.x >> 6;
  const int wm = wave >> 1, wn = wave & 1;
  const int l15 = lane & 15, lg = lane >> 4;
  #pragma unroll
  for (int i = 0; i < 4; ++i) {
    #pragma unroll
    for (int j = 0; j < 4; ++j) {
      const int ncol = n0 + wn * 64 + j * 16 + l15;
      const float bb = bp[ncol];
      #pragma unroll
      for (int r = 0; r < 4; ++r) {
        const int mrow = m0 + wm * 64 + i * 16 + lg * 4 + r;
        if (mrow < MTOT) out[(size_t)mrow * DMODEL + ncol] = acc[i][j][r] + bb;
      }
    }
  }
}

// ---------------- flash attention, swapped-QK^T 32x32 MFMA, in-register softmax ----
// Wave handles 32 q-rows. Lane owns q = q0 + (lane&31); (m,l) lane-local.
// Scores: D[key][q] = mfma(K, Q). PV: out^T[d][q] = mfma(V^T, P).
// C/D layout (32x32): col = lane&31, row = crow(r,hi) = (r&3) + 8*(r>>2) + 4*hi.
//
// P-fragment build (slice = 16 keys, B-frag needs keys hi*8+j at dword j>>1):
//   own dwords:     w0=(crow(0),crow(1)) w1=(crow(2),crow(3)) w2=(crow(4),crow(5)) w3=(crow(6),crow(7))
//   hi=0 lane owns keys (0,1),(2,3),(8,9),(10,11); hi=1 owns (4,5),(6,7),(12,13),(14,15)
//   needed hi=0: (0,1),(2,3),(4,5),(6,7)    = w0, w1, partner w0, partner w1
//   needed hi=1: (8,9),(10,11),(12,13),(14,15) = partner w2, partner w3, w2, w3
template<bool MASK>
__device__ __forceinline__ void attn_tile(int k0, const __bf16* __restrict__ Kp,
                                          const __bf16* __restrict__ Vp,
                                          const bf16x8 (&qf)[4], int l31, int hi,
                                          float& mrun, float& lrun,
                                          f32x16& o0, f32x16& o1) {
  // V fragments issued early (consumed after softmax -> latency hidden)
  const __bf16* vb = Vp + (size_t)l31 * SPAD + k0 + hi * 8;
  bf16x8 vf00 = *(const bf16x8*)(vb);
  bf16x8 vf01 = *(const bf16x8*)(vb + 16);
  bf16x8 vf10 = *(const bf16x8*)(vb + (size_t)32 * SPAD);
  bf16x8 vf11 = *(const bf16x8*)(vb + (size_t)32 * SPAD + 16);

  int krow = k0 + l31;
  if (MASK) krow = krow < SEQ ? krow : SEQ - 1;
  const __bf16* kbase = Kp + (size_t)krow * HDIM + hi * 8;

  f32x16 s;
  #pragma unroll
  for (int r = 0; r < 16; ++r) s[r] = 0.f;
  #pragma unroll
  for (int sl = 0; sl < 4; ++sl) {
    bf16x8 kf = *(const bf16x8*)(kbase + sl * 16);
    s = __builtin_amdgcn_mfma_f32_32x32x16_bf16(kf, qf[sl], s, 0, 0, 0);
  }
  if (MASK) {  // only key k0 (crow==0: r==0 && hi==0) is valid in the tail tile
    #pragma unroll
    for (int r = 1; r < 16; ++r) s[r] = -1e30f;
    if (hi) s[0] = -1e30f;
  }

  // per-q max: lane-local 16 + cross-half exchange
  float mx = s[0];
  #pragma unroll
  for (int r = 1; r < 16; ++r) mx = fmaxf(mx, s[r]);
  const float mloc = pairmax(mx);

  // defer-max (T13): rescale only when tile max exceeds held max by > 8 (log2)
  if (!__all(mloc - mrun <= 8.f)) {
    const float mnew = fmaxf(mrun, mloc);
    const float corr = exp2f(mrun - mnew);
    lrun *= corr;
    #pragma unroll
    for (int r = 0; r < 16; ++r) { o0[r] *= corr; o1[r] *= corr; }
    mrun = mnew;
  }

  float rs = 0.f;
  #pragma unroll
  for (int r = 0; r < 16; ++r) { s[r] = exp2f(s[r] - mrun); rs += s[r]; }
  lrun += pairsum(rs);

  // P -> B-fragment redistribution via known-semantics __shfl_xor(.,32)
  bf16x8 pa[2];
  #pragma unroll
  for (int sl2 = 0; sl2 < 2; ++sl2) {
    const int off = sl2 * 8;
    unsigned w0 = pkbf(s[off + 0], s[off + 1]);
    unsigned w1 = pkbf(s[off + 2], s[off + 3]);
    unsigned w2 = pkbf(s[off + 4], s[off + 5]);
    unsigned w3 = pkbf(s[off + 6], s[off + 7]);
    unsigned p0 = shfl32u(w0), p1 = shfl32u(w1);
    unsigned p2 = shfl32u(w2), p3 = shfl32u(w3);
    unsigned pw[4];
    pw[0] = hi ? p2 : w0;
    pw[1] = hi ? p3 : w1;
    pw[2] = hi ? w2 : p0;
    pw[3] = hi ? w3 : p1;
    __builtin_memcpy(&pa[sl2], pw, 16);
  }

  o0 = __builtin_amdgcn_mfma_f32_32x32x16_bf16(vf00, pa[0], o0, 0, 0, 0);
  o0 = __builtin_amdgcn_mfma_f32_32x32x16_bf16(vf01, pa[1], o0, 0, 0, 0);
  o1 = __builtin_amdgcn_mfma_f32_32x32x16_bf16(vf10, pa[0], o1, 0, 0, 0);
  o1 = __builtin_amdgcn_mfma_f32_32x32x16_bf16(vf11, pa[1], o1, 0, 0, 0);
}

__global__ void __launch_bounds__(64)
attn_kernel(const __bf16* __restrict__ qb, const __bf16* __restrict__ kb,
            const __bf16* __restrict__ vtb, __bf16* __restrict__ ao) {
  const int lane = threadIdx.x;
  const int l31 = lane & 31, hi = lane >> 5;
  const int bh = blockIdx.x / QT32;
  const int qt = blockIdx.x % QT32;
  const __bf16* Qp = qb + (size_t)bh * SEQ * HDIM;
  const __bf16* Kp = kb + (size_t)bh * SEQ * HDIM;
  const __bf16* Vp = vtb + (size_t)bh * HDIM * SPAD;

  const int qidx = qt * 32 + l31;
  const int qc = qidx < SEQ ? qidx : SEQ - 1;
  bf16x8 qf[4];
  #pragma unroll
  for (int sl = 0; sl < 4; ++sl)
    qf[sl] = *(const bf16x8*)&Qp[(size_t)qc * HDIM + sl * 16 + hi * 8];

  f32x16 o0, o1;
  #pragma unroll
  for (int r = 0; r < 16; ++r) { o0[r] = 0.f; o1[r] = 0.f; }
  float mrun = -1e30f, lrun = 0.f;

  for (int kt = 0; kt < 32; ++kt)
    attn_tile<false>(kt * 32, Kp, Vp, qf, l31, hi, mrun, lrun, o0, o1);
  attn_tile<true>(1024, Kp, Vp, qf, l31, hi, mrun, lrun, o0, o1);

  // epilogue: out[q][d], d = t*32 + 8g + 4*hi + u  (crow inverse)
  const int b = bh / NHEAD, h = bh % NHEAD;
  const float inv = 1.f / lrun;
  if (qidx < SEQ) {
    __bf16* base = ao + ((size_t)b * SEQ + qidx) * DMODEL + h * HDIM + hi * 4;
    #pragma unroll
    for (int t = 0; t < 2; ++t) {
      const f32x16& o = t ? o1 : o0;
      #pragma unroll
      for (int g = 0; g < 4; ++g) {
        bf16x4 w;
        #pragma unroll
        for (int u = 0; u < 4; ++u) w[u] = (__bf16)(o[g * 4 + u] * inv);
        *(bf16x4*)(base + t * 32 + g * 8) = w;
      }
    }
  }
}

// ---------------- launcher ----------------
extern "C" void kernel_launch(void* const* d_in, const int* in_sizes, int n_in,
                              void* d_out, int out_size, void* d_ws, size_t ws_size,
                              hipStream_t stream) {
  const float* x  = (const float*)d_in[0];
  const float* Wk = (const float*)d_in[1];
  const float* bk = (const float*)d_in[2];
  const float* Wq = (const float*)d_in[3];
  const float* bq = (const float*)d_in[4];
  const float* Wv = (const float*)d_in[5];
  const float* bv = (const float*)d_in[6];
  const float* Wp = (const float*)d_in[7];
  const float* bp = (const float*)d_in[8];
  float* out = (float*)d_out;

  if (ws_size < WS_NEEDED) return;

  char* ws = (char*)d_ws;
  __bf16* xb  = (__bf16*)(ws + XB_OFF);
  __bf16* wqb = (__bf16*)(ws + WQB_OFF);
  __bf16* wkb = (__bf16*)(ws + WKB_OFF);
  __bf16* wvb = (__bf16*)(ws + WVB_OFF);
  __bf16* wpb = (__bf16*)(ws + WPB_OFF);
  __bf16* qb  = (__bf16*)(ws + QB_OFF);
  __bf16* kb  = (__bf16*)(ws + KB_OFF);
  __bf16* vtb = (__bf16*)(ws + VT_OFF);
  __bf16* ab  = (__bf16*)(ws + AO_OFF);  // aliases xb

  // zero V^T (incl. padded tail columns 1025..1055 -> exact 0 * 0 in PV, no NaN)
  hipMemsetAsync(vtb, 0, VT_SZ, stream);

  {
    const int n_src = MTOT * DMODEL, n_dst = MPAD * DMODEL;
    convert_f32_bf16<<<dim3((n_dst / 4 + 255) / 256), dim3(256), 0, stream>>>(x, xb, n_src, n_dst);
    const int nw = DMODEL * DMODEL;
    convert_w4<<<dim3((nw / 4 + 255) / 256, 4), dim3(256), 0, stream>>>(Wq, Wk, Wv, Wp, wqb);
  }

  gemm_qkv_kernel<<<dim3(MPAD / 128, DMODEL / 128, 3), dim3(256), 0, stream>>>(
      xb, wqb, wkb, wvb, bq, bk, bv, qb, kb, vtb);

  attn_kernel<<<dim3(BHTOT * QT32), dim3(64), 0, stream>>>(qb, kb, vtb, ab);

  gemm_proj_kernel<<<dim3(MPAD / 128, DMODEL / 128), dim3(256), 0, stream>>>(
      ab, wpb, bp, out);
}

// Round 5
// 230.781 us; speedup vs baseline: 1.2454x; 1.0662x over previous
//
#include <hip/hip_runtime.h>
#include <stdint.h>

// ---------------- problem constants ----------------
#define BATCH  8
#define SEQ    1025
#define DMODEL 768
#define NHEAD  12
#define HDIM   64
#define MTOT   (BATCH * SEQ)   // 8200 tokens
#define MPAD   8320            // 65 * 128
#define SPAD   1056            // 33 * 32 (padded key length)
#define BHTOT  (BATCH * NHEAD) // 96
#define QT32   33              // ceil(1025/32) q-tiles of 32
#define QKSCALE 0.18033688011112042f   // 0.125 * log2(e) -> exp2-domain softmax

typedef __bf16 bf16x8 __attribute__((ext_vector_type(8)));
typedef __bf16 bf16x4 __attribute__((ext_vector_type(4)));
typedef float  f32x4  __attribute__((ext_vector_type(4)));
typedef float  f32x16 __attribute__((ext_vector_type(16)));

#if __has_builtin(__builtin_amdgcn_exp2f)
#define EXP2F __builtin_amdgcn_exp2f
#else
#define EXP2F exp2f
#endif

// ---------------- workspace layout (bytes) ----------------
constexpr size_t XB_OFF  = 0;
constexpr size_t XB_SZ   = (size_t)MPAD * DMODEL * 2;
constexpr size_t W_SZ    = (size_t)DMODEL * DMODEL * 2;
constexpr size_t WQB_OFF = XB_OFF + XB_SZ;
constexpr size_t WKB_OFF = WQB_OFF + W_SZ;
constexpr size_t WVB_OFF = WKB_OFF + W_SZ;
constexpr size_t WPB_OFF = WVB_OFF + W_SZ;
constexpr size_t QB_OFF  = WPB_OFF + W_SZ;
constexpr size_t QB_SZ   = (size_t)BHTOT * SEQ * HDIM * 2;
constexpr size_t KB_OFF  = QB_OFF + QB_SZ;
constexpr size_t VT_OFF  = KB_OFF + QB_SZ;
constexpr size_t VT_SZ   = (size_t)BHTOT * HDIM * SPAD * 2;
constexpr size_t AO_OFF  = XB_OFF;                          // alias: xb consumed before attn writes
constexpr size_t WS_NEEDED = VT_OFF + VT_SZ;

// ---------------- helpers ----------------
__device__ __forceinline__ void async16(const void* g, void* l) {
  __builtin_amdgcn_global_load_lds((__attribute__((address_space(1))) void*)g,
                                   (__attribute__((address_space(3))) void*)l,
                                   16, 0, 0);
}

// pack two f32 -> bf16x2 dword (lo = first arg); compiler emits cvt_pk.
__device__ __forceinline__ unsigned pkbf(float lo, float hi) {
  __bf16 l = (__bf16)lo, h = (__bf16)hi;
  unsigned short lb = __builtin_bit_cast(unsigned short, l);
  unsigned short hb = __builtin_bit_cast(unsigned short, h);
  return ((unsigned)hb << 16) | (unsigned)lb;
}
__device__ __forceinline__ unsigned shfl32u(unsigned x) {   // partner half's value
  return (unsigned)__shfl_xor((int)x, 32, 64);
}
__device__ __forceinline__ float pairmax(float x) {  // max(own, lane^32)
  return fmaxf(x, __shfl_xor(x, 32, 64));
}
__device__ __forceinline__ float pairsum(float x) {  // own + lane^32
  return x + __shfl_xor(x, 32, 64);
}

// balanced trees (fp not reassociable by compiler without fast-math)
__device__ __forceinline__ float tree_max16(const f32x16& s) {
  float a0 = fmaxf(s[0], s[1]),   a1 = fmaxf(s[2], s[3]);
  float a2 = fmaxf(s[4], s[5]),   a3 = fmaxf(s[6], s[7]);
  float a4 = fmaxf(s[8], s[9]),   a5 = fmaxf(s[10], s[11]);
  float a6 = fmaxf(s[12], s[13]), a7 = fmaxf(s[14], s[15]);
  float b0 = fmaxf(a0, a1), b1 = fmaxf(a2, a3);
  float b2 = fmaxf(a4, a5), b3 = fmaxf(a6, a7);
  return fmaxf(fmaxf(b0, b1), fmaxf(b2, b3));
}
__device__ __forceinline__ float tree_sum16(const f32x16& s) {
  float a0 = s[0] + s[1],   a1 = s[2] + s[3];
  float a2 = s[4] + s[5],   a3 = s[6] + s[7];
  float a4 = s[8] + s[9],   a5 = s[10] + s[11];
  float a6 = s[12] + s[13], a7 = s[14] + s[15];
  float b0 = a0 + a1, b1 = a2 + a3, b2 = a4 + a5, b3 = a6 + a7;
  return (b0 + b1) + (b2 + b3);
}

// ---------------- fp32 -> bf16 conversion (zero-fills dst beyond n_src) ----------------
__global__ void __launch_bounds__(256)
convert_f32_bf16(const float* __restrict__ src, __bf16* __restrict__ dst,
                 int n_src, int n_dst) {
  int idx = (blockIdx.x * 256 + threadIdx.x) * 4;
  if (idx >= n_dst) return;
  bf16x4 o;
  if (idx + 3 < n_src) {
    float4 v = *(const float4*)&src[idx];
    o[0] = (__bf16)v.x; o[1] = (__bf16)v.y; o[2] = (__bf16)v.z; o[3] = (__bf16)v.w;
  } else {
    #pragma unroll
    for (int t = 0; t < 4; ++t) {
      int k = idx + t;
      o[t] = (k < n_src) ? (__bf16)src[k] : (__bf16)0.f;
    }
  }
  *(bf16x4*)&dst[idx] = o;
}

// 4 weight matrices in one launch; dst regions are contiguous (WQB..WPB).
__global__ void __launch_bounds__(256)
convert_w4(const float* __restrict__ w0, const float* __restrict__ w1,
           const float* __restrict__ w2, const float* __restrict__ w3,
           __bf16* __restrict__ dst) {
  const int which = blockIdx.y;
  const float* src = (which == 0) ? w0 : (which == 1) ? w1 : (which == 2) ? w2 : w3;
  __bf16* d = dst + (size_t)which * DMODEL * DMODEL;
  int idx = (blockIdx.x * 256 + threadIdx.x) * 4;
  if (idx >= DMODEL * DMODEL) return;
  float4 v = *(const float4*)&src[idx];
  bf16x4 o;
  o[0] = (__bf16)v.x; o[1] = (__bf16)v.y; o[2] = (__bf16)v.z; o[3] = (__bf16)v.w;
  *(bf16x4*)&d[idx] = o;
}

// ---------------- shared 128x128 GEMM core: C = A @ W^T ----------------
__device__ __forceinline__ void gemm_core(const __bf16* __restrict__ A,
                                          const __bf16* __restrict__ W,
                                          __bf16* As, __bf16* Bs,
                                          int m0, int n0, f32x4 acc[4][4]) {
  const int tid  = threadIdx.x;
  const int lane = tid & 63;
  const int wave = tid >> 6;
  const int wm = wave >> 1, wn = wave & 1;
  const int l15 = lane & 15, lg = lane >> 4;

  for (int kt = 0; kt < DMODEL; kt += 64) {
    __syncthreads();
    #pragma unroll
    for (int i = 0; i < 4; ++i) {
      int e = (i * 256 + tid) * 8;
      int r = e >> 6, c = e & 63;
      async16(A + (size_t)(m0 + r) * DMODEL + kt + c, As + e);
      async16(W + (size_t)(n0 + r) * DMODEL + kt + c, Bs + e);
    }
    __syncthreads();
    #pragma unroll
    for (int kk = 0; kk < 2; ++kk) {
      bf16x8 af[4], bfr[4];
      #pragma unroll
      for (int i = 0; i < 4; ++i)
        af[i] = *(const bf16x8*)&As[(wm * 64 + i * 16 + l15) * 64 + kk * 32 + lg * 8];
      #pragma unroll
      for (int j = 0; j < 4; ++j)
        bfr[j] = *(const bf16x8*)&Bs[(wn * 64 + j * 16 + l15) * 64 + kk * 32 + lg * 8];
      #pragma unroll
      for (int i = 0; i < 4; ++i)
        #pragma unroll
        for (int j = 0; j < 4; ++j)
          acc[i][j] = __builtin_amdgcn_mfma_f32_16x16x32_bf16(af[i], bfr[j], acc[i][j], 0, 0, 0);
    }
  }
}

// ---------------- QKV projection ----------------
__global__ void __launch_bounds__(256)
gemm_qkv_kernel(const __bf16* __restrict__ xb,
                const __bf16* __restrict__ wqb, const __bf16* __restrict__ wkb,
                const __bf16* __restrict__ wvb,
                const float* __restrict__ bq, const float* __restrict__ bk,
                const float* __restrict__ bv,
                __bf16* __restrict__ qb, __bf16* __restrict__ kb,
                __bf16* __restrict__ vtb) {
  __shared__ __bf16 As[128 * 64];
  __shared__ __bf16 Bs[128 * 64];
  const int mode = blockIdx.z;
  const __bf16* W  = (mode == 0) ? wqb : (mode == 1) ? wkb : wvb;
  const float* bias = (mode == 0) ? bq : (mode == 1) ? bk : bv;
  const int m0 = blockIdx.x * 128, n0 = blockIdx.y * 128;

  f32x4 acc[4][4];
  #pragma unroll
  for (int i = 0; i < 4; ++i)
    #pragma unroll
    for (int j = 0; j < 4; ++j) acc[i][j] = (f32x4){0.f, 0.f, 0.f, 0.f};

  gemm_core(xb, W, As, Bs, m0, n0, acc);

  const int lane = threadIdx.x & 63;
  const int wave = threadIdx.x >> 6;
  const int wm = wave >> 1, wn = wave & 1;
  const int l15 = lane & 15, lg = lane >> 4;
  #pragma unroll
  for (int i = 0; i < 4; ++i) {
    #pragma unroll
    for (int j = 0; j < 4; ++j) {
      const int ncol = n0 + wn * 64 + j * 16 + l15;
      const float bb = bias[ncol];
      const int h = ncol >> 6, hd = ncol & 63;
      #pragma unroll
      for (int r = 0; r < 4; ++r) {
        const int mrow = m0 + wm * 64 + i * 16 + lg * 4 + r;
        if (mrow < MTOT) {
          float val = acc[i][j][r] + bb;
          const int b = mrow / SEQ;
          const int s = mrow - b * SEQ;
          const int bh = b * NHEAD + h;
          if (mode == 2)
            vtb[((size_t)bh * HDIM + hd) * SPAD + s] = (__bf16)val;
          else if (mode == 0)
            qb[((size_t)bh * SEQ + s) * HDIM + hd] = (__bf16)(val * QKSCALE);
          else
            kb[((size_t)bh * SEQ + s) * HDIM + hd] = (__bf16)val;
        }
      }
    }
  }
}

// ---------------- output projection ----------------
__global__ void __launch_bounds__(256)
gemm_proj_kernel(const __bf16* __restrict__ ab, const __bf16* __restrict__ wpb,
                 const float* __restrict__ bp, float* __restrict__ out) {
  __shared__ __bf16 As[128 * 64];
  __shared__ __bf16 Bs[128 * 64];
  const int m0 = blockIdx.x * 128, n0 = blockIdx.y * 128;

  f32x4 acc[4][4];
  #pragma unroll
  for (int i = 0; i < 4; ++i)
    #pragma unroll
    for (int j = 0; j < 4; ++j) acc[i][j] = (f32x4){0.f, 0.f, 0.f, 0.f};

  gemm_core(ab, wpb, As, Bs, m0, n0, acc);

  const int lane = threadIdx.x & 63;
  const int wave = threadIdx.x >> 6;
  const int wm = wave >> 1, wn = wave & 1;
  const int l15 = lane & 15, lg = lane >> 4;
  #pragma unroll
  for (int i = 0; i < 4; ++i) {
    #pragma unroll
    for (int j = 0; j < 4; ++j) {
      const int ncol = n0 + wn * 64 + j * 16 + l15;
      const float bb = bp[ncol];
      #pragma unroll
      for (int r = 0; r < 4; ++r) {
        const int mrow = m0 + wm * 64 + i * 16 + lg * 4 + r;
        if (mrow < MTOT) out[(size_t)mrow * DMODEL + ncol] = acc[i][j][r] + bb;
      }
    }
  }
}

// ---------------- flash attention: split-K 2-wave blocks, swapped-QK^T 32x32 ----
// Block = 128 threads = 2 waves, one (bh, 32-row q-tile). Wave w handles K-tiles
// t = w, w+2, ... with private online-softmax state; exact merge via LDS at end.
// Lane owns q = q0 + (lane&31). Scores: D[key][q] = mfma(K, Q).
// PV: out^T[d][q] = mfma(V^T, P). C/D: col = lane&31, row = crow(r,hi) = (r&3)+8*(r>>2)+4*hi.
template<bool MASK>
__device__ __forceinline__ void attn_tile(int k0, const __bf16* __restrict__ Kp,
                                          const __bf16* __restrict__ Vp,
                                          const bf16x8 (&qf)[4], int l31, int hi,
                                          float& mrun, float& lrun,
                                          f32x16& o0, f32x16& o1) {
  // V fragments issued early (consumed after softmax -> latency hidden)
  const __bf16* vb = Vp + (size_t)l31 * SPAD + k0 + hi * 8;
  bf16x8 vf00 = *(const bf16x8*)(vb);
  bf16x8 vf01 = *(const bf16x8*)(vb + 16);
  bf16x8 vf10 = *(const bf16x8*)(vb + (size_t)32 * SPAD);
  bf16x8 vf11 = *(const bf16x8*)(vb + (size_t)32 * SPAD + 16);

  int krow = k0 + l31;
  if (MASK) krow = krow < SEQ ? krow : SEQ - 1;
  const __bf16* kbase = Kp + (size_t)krow * HDIM + hi * 8;

  f32x16 s;
  #pragma unroll
  for (int r = 0; r < 16; ++r) s[r] = 0.f;
  #pragma unroll
  for (int sl = 0; sl < 4; ++sl) {
    bf16x8 kf = *(const bf16x8*)(kbase + sl * 16);
    s = __builtin_amdgcn_mfma_f32_32x32x16_bf16(kf, qf[sl], s, 0, 0, 0);
  }
  if (MASK) {  // only key k0 (crow==0: r==0 && hi==0) is valid in the tail tile
    #pragma unroll
    for (int r = 1; r < 16; ++r) s[r] = -1e30f;
    if (hi) s[0] = -1e30f;
  }

  // per-q max: balanced lane-local tree + cross-half exchange
  const float mloc = pairmax(tree_max16(s));

  // defer-max (T13): rescale only when tile max exceeds held max by > 8 (log2)
  if (!__all(mloc - mrun <= 8.f)) {
    const float mnew = fmaxf(mrun, mloc);
    const float corr = EXP2F(mrun - mnew);
    lrun *= corr;
    #pragma unroll
    for (int r = 0; r < 16; ++r) { o0[r] *= corr; o1[r] *= corr; }
    mrun = mnew;
  }

  #pragma unroll
  for (int r = 0; r < 16; ++r) s[r] = EXP2F(s[r] - mrun);
  lrun += pairsum(tree_sum16(s));

  // P -> B-fragment redistribution via __shfl_xor(.,32)
  bf16x8 pa[2];
  #pragma unroll
  for (int sl2 = 0; sl2 < 2; ++sl2) {
    const int off = sl2 * 8;
    unsigned w0 = pkbf(s[off + 0], s[off + 1]);
    unsigned w1 = pkbf(s[off + 2], s[off + 3]);
    unsigned w2 = pkbf(s[off + 4], s[off + 5]);
    unsigned w3 = pkbf(s[off + 6], s[off + 7]);
    unsigned p0 = shfl32u(w0), p1 = shfl32u(w1);
    unsigned p2 = shfl32u(w2), p3 = shfl32u(w3);
    unsigned pw[4];
    pw[0] = hi ? p2 : w0;
    pw[1] = hi ? p3 : w1;
    pw[2] = hi ? w2 : p0;
    pw[3] = hi ? w3 : p1;
    __builtin_memcpy(&pa[sl2], pw, 16);
  }

  o0 = __builtin_amdgcn_mfma_f32_32x32x16_bf16(vf00, pa[0], o0, 0, 0, 0);
  o0 = __builtin_amdgcn_mfma_f32_32x32x16_bf16(vf01, pa[1], o0, 0, 0, 0);
  o1 = __builtin_amdgcn_mfma_f32_32x32x16_bf16(vf10, pa[0], o1, 0, 0, 0);
  o1 = __builtin_amdgcn_mfma_f32_32x32x16_bf16(vf11, pa[1], o1, 0, 0, 0);
}

__global__ void __launch_bounds__(128)
attn_kernel(const __bf16* __restrict__ qb, const __bf16* __restrict__ kb,
            const __bf16* __restrict__ vtb, __bf16* __restrict__ ao) {
  __shared__ float obuf[32][64];   // [reg r][lane] -> conflict-free both directions
  __shared__ float mbuf[64], lbuf[64];

  const int tid  = threadIdx.x;
  const int wid  = tid >> 6;
  const int lane = tid & 63;
  const int l31 = lane & 31, hi = (lane >> 5) & 1;
  const int bh = blockIdx.x / QT32;
  const int qt = blockIdx.x % QT32;
  const __bf16* Qp = qb + (size_t)bh * SEQ * HDIM;
  const __bf16* Kp = kb + (size_t)bh * SEQ * HDIM;
  const __bf16* Vp = vtb + (size_t)bh * HDIM * SPAD;

  const int qidx = qt * 32 + l31;
  const int qc = qidx < SEQ ? qidx : SEQ - 1;
  bf16x8 qf[4];
  #pragma unroll
  for (int sl = 0; sl < 4; ++sl)
    qf[sl] = *(const bf16x8*)&Qp[(size_t)qc * HDIM + sl * 16 + hi * 8];

  f32x16 o0, o1;
  #pragma unroll
  for (int r = 0; r < 16; ++r) { o0[r] = 0.f; o1[r] = 0.f; }
  float mrun = -1e30f, lrun = 0.f;

  // wave `wid` takes tiles wid, wid+2, ...; tail tile (t=32, 1 valid key) is even -> wave 0
  for (int t = wid; t < 32; t += 2)
    attn_tile<false>(t * 32, Kp, Vp, qf, l31, hi, mrun, lrun, o0, o1);
  if (wid == 0)
    attn_tile<true>(1024, Kp, Vp, qf, l31, hi, mrun, lrun, o0, o1);

  // ---- merge the two waves' online-softmax states ----
  if (wid == 1) {
    mbuf[lane] = mrun;
    lbuf[lane] = lrun;
    #pragma unroll
    for (int r = 0; r < 16; ++r) { obuf[r][lane] = o0[r]; obuf[16 + r][lane] = o1[r]; }
  }
  __syncthreads();
  if (wid != 0) return;

  const float m1 = mbuf[lane], l1 = lbuf[lane];
  const float M  = fmaxf(mrun, m1);
  const float c0 = EXP2F(mrun - M);
  const float c1 = EXP2F(m1 - M);
  const float inv = 1.f / (lrun * c0 + l1 * c1);

  const int b = bh / NHEAD, h = bh % NHEAD;
  if (qidx < SEQ) {
    __bf16* base = ao + ((size_t)b * SEQ + qidx) * DMODEL + h * HDIM + hi * 4;
    #pragma unroll
    for (int t = 0; t < 2; ++t) {
      const f32x16& o = t ? o1 : o0;
      #pragma unroll
      for (int g = 0; g < 4; ++g) {
        bf16x4 w;
        #pragma unroll
        for (int u = 0; u < 4; ++u) {
          const int r = g * 4 + u;
          const float merged = o[r] * c0 + obuf[t * 16 + r][lane] * c1;
          w[u] = (__bf16)(merged * inv);
        }
        *(bf16x4*)(base + t * 32 + g * 8) = w;
      }
    }
  }
}

// ---------------- launcher ----------------
extern "C" void kernel_launch(void* const* d_in, const int* in_sizes, int n_in,
                              void* d_out, int out_size, void* d_ws, size_t ws_size,
                              hipStream_t stream) {
  const float* x  = (const float*)d_in[0];
  const float* Wk = (const float*)d_in[1];
  const float* bk = (const float*)d_in[2];
  const float* Wq = (const float*)d_in[3];
  const float* bq = (const float*)d_in[4];
  const float* Wv = (const float*)d_in[5];
  const float* bv = (const float*)d_in[6];
  const float* Wp = (const float*)d_in[7];
  const float* bp = (const float*)d_in[8];
  float* out = (float*)d_out;

  if (ws_size < WS_NEEDED) return;

  char* ws = (char*)d_ws;
  __bf16* xb  = (__bf16*)(ws + XB_OFF);
  __bf16* wqb = (__bf16*)(ws + WQB_OFF);
  __bf16* wkb = (__bf16*)(ws + WKB_OFF);
  __bf16* wvb = (__bf16*)(ws + WVB_OFF);
  __bf16* wpb = (__bf16*)(ws + WPB_OFF);
  __bf16* qb  = (__bf16*)(ws + QB_OFF);
  __bf16* kb  = (__bf16*)(ws + KB_OFF);
  __bf16* vtb = (__bf16*)(ws + VT_OFF);
  __bf16* ab  = (__bf16*)(ws + AO_OFF);  // aliases xb

  // zero V^T (incl. padded tail columns 1025..1055 -> exact 0 * 0 in PV, no NaN)
  hipMemsetAsync(vtb, 0, VT_SZ, stream);

  {
    const int n_src = MTOT * DMODEL, n_dst = MPAD * DMODEL;
    convert_f32_bf16<<<dim3((n_dst / 4 + 255) / 256), dim3(256), 0, stream>>>(x, xb, n_src, n_dst);
    const int nw = DMODEL * DMODEL;
    convert_w4<<<dim3((nw / 4 + 255) / 256, 4), dim3(256), 0, stream>>>(Wq, Wk, Wv, Wp, wqb);
  }

  gemm_qkv_kernel<<<dim3(MPAD / 128, DMODEL / 128, 3), dim3(256), 0, stream>>>(
      xb, wqb, wkb, wvb, bq, bk, bv, qb, kb, vtb);

  attn_kernel<<<dim3(BHTOT * QT32), dim3(128), 0, stream>>>(qb, kb, vtb, ab);

  gemm_proj_kernel<<<dim3(MPAD / 128, DMODEL / 128), dim3(256), 0, stream>>>(
      ab, wpb, bp, out);
}